// Round 13
// baseline (326.884 us; speedup 1.0000x reference)
//
#include <hip/hip_runtime.h>
#include <math.h>

typedef unsigned int uint;
typedef unsigned short ushort;

#define NROWS 65536
#define KCB   1024
#define DDIM  256
#define MARGIN 0.15f

// d_out layout (floats)
#define OUT_ZQ    0
#define OUT_LOSS  16777216
#define OUT_IDX   16777217
#define OUT_PERP  16842753
#define OUT_USAGE 16842754

typedef __attribute__((ext_vector_type(8))) short s16x8;
typedef __attribute__((ext_vector_type(4))) float f32x4;
typedef __attribute__((ext_vector_type(4))) double f64x4;

__device__ __forceinline__ ushort bf16rne(float x) {
  uint u = __float_as_uint(x);
  return (ushort)((u + 0x7FFFu + ((u >> 16) & 1u)) >> 16);
}
__device__ __forceinline__ float bf2f(ushort h) {
  return __uint_as_float((uint)h << 16);
}

// ---------------------------------------------------------------------------
// Kernel 1: codebook = normalize(lb @ W.T) * 16 in fp64 (LDS-staged W);
// emits transposed fp64 (cb64T[j][k] for refine), fp32, and bf16-hi copy.
// ---------------------------------------------------------------------------
__global__ __launch_bounds__(256) void cb_kernel(const float* __restrict__ lb,
                                                 const float* __restrict__ W,
                                                 double* __restrict__ cb64T,
                                                 float* __restrict__ cb32,
                                                 double* __restrict__ c264,
                                                 ushort* __restrict__ ch) {
  const int k = blockIdx.x;
  const int t = threadIdx.x;
  __shared__ float lb_sh[256];
  __shared__ float W_sh[256 * 66];
  __shared__ double red[256];

  lb_sh[t] = lb[k * 256 + t];

  double acc = 0.0;
  for (int jt = 0; jt < 4; ++jt) {
    __syncthreads();
#pragma unroll
    for (int i = 0; i < 16; ++i) {
      int qid = t + 256 * i;
      int row = qid >> 4;
      int q   = qid & 15;
      float4 v = *(const float4*)&W[row * 256 + jt * 64 + q * 4];
      float* dst = &W_sh[row * 66 + q * 4];
      dst[0] = v.x; dst[1] = v.y; dst[2] = v.z; dst[3] = v.w;
    }
    __syncthreads();
#pragma unroll
    for (int jj = 0; jj < 64; ++jj) {
      acc += (double)lb_sh[jt * 64 + jj] * (double)W_sh[t * 66 + jj];
    }
  }

  red[t] = acc * acc;
  __syncthreads();
  for (int s = 128; s > 0; s >>= 1) {
    if (t < s) red[t] += red[t + s];
    __syncthreads();
  }
  double norm  = sqrt(red[0]);
  double scale = 16.0 / fmax(norm, 1e-12);
  double v     = acc * scale;
  cb64T[(size_t)t * 1024 + k] = v;        // transposed for refine
  float cf = (float)v;
  cb32[k * 256 + t] = cf;
  ch[k * 256 + t] = bf16rne(cf);

  __syncthreads();
  red[t] = v * v;
  __syncthreads();
  for (int s = 128; s > 0; s >>= 1) {
    if (t < s) red[t] += red[t + s];
    __syncthreads();
  }
  if (t == 0) c264[k] = red[0];
}

// ---------------------------------------------------------------------------
// Kernel 2: fused MFMA argmax + gather, 16x16x32 (round-13: full-K tile).
// LDS tile = 128 codes x ALL 256 k (64 KB), double-buffered = 128 KB ->
// only 8 nt-tiles => 8 barriers total (rounds 9-12 paid 32-64 vmcnt(0)
// drains; that plus CU-wide LDS-read issue was the measured cost).
// Block = 128 z-rows: 4 waves x 2 register rowsets; each ds_read_b128 of a
// code fragment feeds 4 MFMAs (hi/lo x rowsetA/B). K-major chunk layout
// [kc:8][q:4][row:128]x16B -- conflict-free (0 measured r8-r12), linear
// gload_lds dest, per-lane source. launch_bounds(256,1): ~200 VGPR, 1
// block/CU, per-wave ILP (256 indep MFMA between barriers) hides latency.
// ---------------------------------------------------------------------------
__global__ __launch_bounds__(256, 1) void argmax_mfma(const float* __restrict__ z,
                                                      const ushort* __restrict__ ch,
                                                      const float* __restrict__ cb32,
                                                      float* __restrict__ out_idx,
                                                      int* __restrict__ idx_int,
                                                      int* __restrict__ flagc,
                                                      int* __restrict__ flagr,
                                                      float* __restrict__ zq,
                                                      double* __restrict__ msep,
                                                      int* __restrict__ counts) {
  const int t     = threadIdx.x;
  const int lane  = t & 63;
  const int w     = t >> 6;
  const int ra    = lane & 15;     // z-row / code-row within 16-group
  const int q4    = lane >> 4;     // K 8-elem subchunk within a 32-k chunk
  const int mtile = blockIdx.x;

  __shared__ alignas(128) char cbuf[2][65536];
  __shared__ int    sidx[128];
  __shared__ double partial[4];

  // ---- z fragments: TWO rows per lane (rowA = rbase+ra, rowB = +16) ----
  s16x8 zha[8], zla[8], zhb[8], zlb[8];
  const int rbase = mtile * 128 + w * 32;
#pragma unroll
  for (int c = 0; c < 8; ++c) {
    {
      const float* zp = &z[(size_t)(rbase + ra) * 256 + c * 32 + q4 * 8];
      float4 f0 = *(const float4*)zp;
      float4 f1 = *(const float4*)(zp + 4);
      float xs[8] = {f0.x, f0.y, f0.z, f0.w, f1.x, f1.y, f1.z, f1.w};
#pragma unroll
      for (int e = 0; e < 8; ++e) {
        ushort hh = bf16rne(xs[e]);
        zha[c][e] = (short)hh;
        zla[c][e] = (short)bf16rne(xs[e] - bf2f(hh));
      }
    }
    {
      const float* zp = &z[(size_t)(rbase + 16 + ra) * 256 + c * 32 + q4 * 8];
      float4 f0 = *(const float4*)zp;
      float4 f1 = *(const float4*)(zp + 4);
      float xs[8] = {f0.x, f0.y, f0.z, f0.w, f1.x, f1.y, f1.z, f1.w};
#pragma unroll
      for (int e = 0; e < 8; ++e) {
        ushort hh = bf16rne(xs[e]);
        zhb[c][e] = (short)hh;
        zlb[c][e] = (short)bf16rne(xs[e] - bf2f(hh));
      }
    }
  }

  // ---- staging: one nt-tile = 4096 slots of 16B; slot s: row=s&127,
  //      q=(s>>7)&3, kc=s>>9. Linear LDS dest, per-lane global source. ----
  auto stage = [&](int buf, int nt) {
#pragma unroll
    for (int i = 0; i < 16; ++i) {
      int s   = w * 1024 + i * 64 + lane;
      int row = s & 127;
      int q   = (s >> 7) & 3;
      int kc  = s >> 9;
      const ushort* src = ch + (size_t)(nt * 128 + row) * 256 + kc * 32 + q * 8;
      __builtin_amdgcn_global_load_lds(
          (const __attribute__((address_space(1))) void*)src,
          (__attribute__((address_space(3))) void*)(&cbuf[buf][0] + (w * 1024 + i * 64) * 16),
          16, 0, 0);
    }
  };

  float m1a = -3.0e38f, m2a = -3.0e38f;
  float m1b = -3.0e38f, m2b = -3.0e38f;
  int   i1a = 0, i1b = 0;

  stage(0, 0);
  __syncthreads();

#pragma unroll 1
  for (int nt = 0; nt < 8; ++nt) {
    const int cur = nt & 1;
    if (nt < 7) stage(cur ^ 1, nt + 1);

    f32x4 acca[8] = {f32x4(0.f), f32x4(0.f), f32x4(0.f), f32x4(0.f),
                     f32x4(0.f), f32x4(0.f), f32x4(0.f), f32x4(0.f)};
    f32x4 accb[8] = {f32x4(0.f), f32x4(0.f), f32x4(0.f), f32x4(0.f),
                     f32x4(0.f), f32x4(0.f), f32x4(0.f), f32x4(0.f)};

    const char* cbb = &cbuf[cur][0];
#pragma unroll
    for (int kc = 0; kc < 8; ++kc) {
      const s16x8 bha = zha[kc];
      const s16x8 bla = zla[kc];
      const s16x8 bhb = zhb[kc];
      const s16x8 blb = zlb[kc];
#pragma unroll
      for (int cg = 0; cg < 8; ++cg) {
        s16x8 a = *(const s16x8*)(cbb + kc * 8192 + q4 * 2048 + (cg * 16 + ra) * 16);
        acca[cg] = __builtin_amdgcn_mfma_f32_16x16x32_bf16(a, bha, acca[cg], 0, 0, 0);
        acca[cg] = __builtin_amdgcn_mfma_f32_16x16x32_bf16(a, bla, acca[cg], 0, 0, 0);
        accb[cg] = __builtin_amdgcn_mfma_f32_16x16x32_bf16(a, bhb, accb[cg], 0, 0, 0);
        accb[cg] = __builtin_amdgcn_mfma_f32_16x16x32_bf16(a, blb, accb[cg], 0, 0, 0);
      }
    }

    // fold this nt's 128 codes into both rowsets' (m1, m2, i1).
    // D layout (verified r8-r12): col = lane&15 = zrow; code-row = q4*4+j.
#pragma unroll
    for (int cg = 0; cg < 8; ++cg) {
#pragma unroll
      for (int j = 0; j < 4; ++j) {
        const int code = nt * 128 + cg * 16 + q4 * 4 + j;
        float va = acca[cg][j];
        if (va > m1a) { m2a = m1a; m1a = va; i1a = code; }
        else          { m2a = fmaxf(m2a, va); }
        float vb = accb[cg][j];
        if (vb > m1b) { m2b = m1b; m1b = vb; i1b = code; }
        else          { m2b = fmaxf(m2b, vb); }
      }
    }
    __syncthreads();
  }

  // ---- cross-lane merge across the 4 K-quarter copies of each z-row ----
#pragma unroll
  for (int off = 16; off <= 32; off <<= 1) {
    float om1 = __shfl_xor(m1a, off);
    float om2 = __shfl_xor(m2a, off);
    int   oi1 = __shfl_xor(i1a, off);
    if (om1 > m1a || (om1 == m1a && oi1 < i1a)) {
      m2a = fmaxf(m1a, om2); m1a = om1; i1a = oi1;
    } else {
      m2a = fmaxf(m2a, om1);
    }
    om1 = __shfl_xor(m1b, off);
    om2 = __shfl_xor(m2b, off);
    oi1 = __shfl_xor(i1b, off);
    if (om1 > m1b || (om1 == m1b && oi1 < i1b)) {
      m2b = fmaxf(m1b, om2); m1b = om1; i1b = oi1;
    } else {
      m2b = fmaxf(m2b, om1);
    }
  }

  if (lane < 16) {
    const int rowA = rbase + lane;
    sidx[w * 32 + lane] = i1a;
    idx_int[rowA] = i1a;
    out_idx[rowA] = (float)i1a;
    if (m1a - m2a < MARGIN) {
      int pos = atomicAdd(flagc, 1);
      flagr[pos] = rowA;
    }
    const int rowB = rbase + 16 + lane;
    sidx[w * 32 + 16 + lane] = i1b;
    idx_int[rowB] = i1b;
    out_idx[rowB] = (float)i1b;
    if (m1b - m2b < MARGIN) {
      int pos = atomicAdd(flagc, 1);
      flagr[pos] = rowB;
    }
  }
  __syncthreads();

  // ---- fused gather: z_q write, mse partial, counts ----
  double msum = 0.0;
  for (int rr = w; rr < 128; rr += 4) {
    const int code = sidx[rr];
    const int grow = mtile * 128 + rr;
    float4 c = *(const float4*)&cb32[(size_t)code * 256 + lane * 4];
    *(float4*)&zq[(size_t)grow * 256 + lane * 4] = c;
    float4 zr = *(const float4*)&z[(size_t)grow * 256 + lane * 4];
    double d;
    d = (double)c.x - (double)zr.x; msum += d * d;
    d = (double)c.y - (double)zr.y; msum += d * d;
    d = (double)c.z - (double)zr.z; msum += d * d;
    d = (double)c.w - (double)zr.w; msum += d * d;
    if (lane == 0) atomicAdd(&counts[code], 1);
  }
#pragma unroll
  for (int off = 32; off > 0; off >>= 1) msum += __shfl_xor(msum, off);
  if (lane == 0) partial[w] = msum;
  __syncthreads();
  if (t == 0) msep[mtile] = partial[0] + partial[1] + partial[2] + partial[3];
}

// ---------------------------------------------------------------------------
// Kernel 3: exact fp64 re-solve of flagged rows (8-row batching, round-11
// verified). Each cb64T double4 load feeds 8 rows x 4 codes = 32 f64 FMA.
// Patches idx, z_q, counts, mse delta per changed row.
// ---------------------------------------------------------------------------
__global__ __launch_bounds__(256) void refine_kernel(const float* __restrict__ z,
                                                     const double* __restrict__ cb64T,
                                                     const double* __restrict__ c264,
                                                     const float* __restrict__ cb32,
                                                     const int* __restrict__ flagc,
                                                     const int* __restrict__ flagr,
                                                     int* __restrict__ idx_int,
                                                     float* __restrict__ out_idx,
                                                     float* __restrict__ zq,
                                                     int* __restrict__ counts,
                                                     double* __restrict__ msedelta) {
  const int cnt = *flagc;
  const int t   = threadIdx.x;
  __shared__ double z_sh[8][256];
  __shared__ double rs[256];
  __shared__ int    ri[256];
  __shared__ int    shI, shO;
  __shared__ double red[256];

  const int nbatch = (cnt + 7) >> 3;
  for (int b = blockIdx.x; b < nbatch; b += gridDim.x) {
    const int r0 = b * 8;
    const int nr = min(8, cnt - r0);
    __syncthreads();   // z_sh reuse across batches
#pragma unroll
    for (int r = 0; r < 8; ++r) {
      int rr = (r < nr) ? flagr[r0 + r] : flagr[r0];
      z_sh[r][t] = (double)z[(size_t)rr * DDIM + t];
    }
    __syncthreads();

    double a0[8], a1[8], a2[8], a3[8];
#pragma unroll
    for (int r = 0; r < 8; ++r) { a0[r] = 0.0; a1[r] = 0.0; a2[r] = 0.0; a3[r] = 0.0; }

#pragma unroll 1
    for (int j = 0; j < 256; j += 2) {
      f64x4 cv0 = *(const f64x4*)&cb64T[(size_t)j * 1024 + t * 4];
      f64x4 cv1 = *(const f64x4*)&cb64T[(size_t)(j + 1) * 1024 + t * 4];
#pragma unroll
      for (int r = 0; r < 8; ++r) {
        double zv = z_sh[r][j];
        a0[r] += zv * cv0[0];
        a1[r] += zv * cv0[1];
        a2[r] += zv * cv0[2];
        a3[r] += zv * cv0[3];
      }
#pragma unroll
      for (int r = 0; r < 8; ++r) {
        double zv = z_sh[r][j + 1];
        a0[r] += zv * cv1[0];
        a1[r] += zv * cv1[1];
        a2[r] += zv * cv1[2];
        a3[r] += zv * cv1[3];
      }
    }

    f64x4 c2 = *(const f64x4*)&c264[t * 4];
#pragma unroll
    for (int r = 0; r < 8; ++r) {
      if (r >= nr) continue;     // nr is block-uniform -> barriers legal
      double bb = 2.0 * a0[r] - c2[0];  int bi_ = t * 4;
      double s1 = 2.0 * a1[r] - c2[1];  if (s1 > bb) { bb = s1; bi_ = t * 4 + 1; }
      double s2 = 2.0 * a2[r] - c2[2];  if (s2 > bb) { bb = s2; bi_ = t * 4 + 2; }
      double s3 = 2.0 * a3[r] - c2[3];  if (s3 > bb) { bb = s3; bi_ = t * 4 + 3; }
      rs[t] = bb; ri[t] = bi_;
      __syncthreads();
      for (int s = 128; s > 0; s >>= 1) {
        if (t < s) {
          if (rs[t + s] > rs[t] || (rs[t + s] == rs[t] && ri[t + s] < ri[t])) {
            rs[t] = rs[t + s]; ri[t] = ri[t + s];
          }
        }
        __syncthreads();
      }
      const int row = flagr[r0 + r];
      if (t == 0) {
        int I = ri[0];
        shO = idx_int[row];
        shI = I;
        if (I != shO) {
          idx_int[row] = I;
          out_idx[row] = (float)I;
          atomicSub(&counts[shO], 1);
          atomicAdd(&counts[I], 1);
        }
      }
      __syncthreads();
      const int I = shI, O = shO;
      if (I != O) {
        float zz = (float)z_sh[r][t];
        float cn = cb32[(size_t)I * DDIM + t];
        float co = cb32[(size_t)O * DDIM + t];
        zq[(size_t)row * DDIM + t] = cn;
        double dn = (double)cn - (double)zz;
        double dd = (double)co - (double)zz;
        red[t] = dn * dn - dd * dd;
        __syncthreads();
        for (int s = 128; s > 0; s >>= 1) {
          if (t < s) red[t] += red[t + s];
          __syncthreads();
        }
        if (t == 0) atomicAdd(msedelta, red[0]);
      }
      __syncthreads();
    }
  }
}

// ---------------------------------------------------------------------------
// Kernel 4: scalars -- vq_loss, perplexity, codebook_usage.
// ---------------------------------------------------------------------------
__global__ __launch_bounds__(256) void finalize_kernel(const int* __restrict__ counts,
                                                       const double* __restrict__ msep,
                                                       const double* __restrict__ msedelta,
                                                       float* __restrict__ out) {
  const int t = threadIdx.x;
  double ms = 0.0;
#pragma unroll
  for (int i = t; i < 512; i += 256) ms += msep[i];
  if (t == 0) ms += *msedelta;

  double ent = 0.0;
  int used = 0;
#pragma unroll
  for (int i = t; i < KCB; i += 256) {
    int c = counts[i];
    if (c > 0) used++;
    double p = (double)c / (double)NROWS;
    ent += p * log(p + 1e-10);
  }
  __shared__ double se[256];
  __shared__ double sm[256];
  __shared__ int    su[256];
  se[t] = ent; sm[t] = ms; su[t] = used;
  __syncthreads();
  for (int s = 128; s > 0; s >>= 1) {
    if (t < s) { se[t] += se[t + s]; sm[t] += sm[t + s]; su[t] += su[t + s]; }
    __syncthreads();
  }
  if (t == 0) {
    double mse = sm[0] / ((double)NROWS * (double)DDIM);
    out[OUT_LOSS]  = (float)(1.25 * mse);
    out[OUT_PERP]  = (float)exp(-se[0]);
    out[OUT_USAGE] = (float)((double)su[0] / (double)KCB);
  }
}

// ---------------------------------------------------------------------------
extern "C" void kernel_launch(void* const* d_in, const int* in_sizes, int n_in,
                              void* d_out, int out_size, void* d_ws, size_t ws_size,
                              hipStream_t stream) {
  const float* z  = (const float*)d_in[0];   // [65536][256]
  const float* lb = (const float*)d_in[1];   // [1024][256]
  const float* W  = (const float*)d_in[2];   // [256][256]
  float* out = (float*)d_out;

  char* base = (char*)d_ws;
  double* cb64T   = (double*)(base + 0x000000);  // 2 MB (transposed [j][k])
  ushort* ch      = (ushort*)(base + 0x200000);  // 512 KB
  float*  cb32    = (float*) (base + 0x300000);  // 1 MB
  double* c264    = (double*)(base + 0x400000);  // 8 KB
  int*    idxi    = (int*)   (base + 0x402000);  // 256 KB
  int*    flagr   = (int*)   (base + 0x442000);  // 256 KB
  int*    counts  = (int*)   (base + 0x482000);  // 4 KB   } one zeroed
  int*    flagc   = (int*)   (base + 0x483000);  // 4 B    } contiguous
  double* msedel  = (double*)(base + 0x483008);  // 8 B    } region
  double* msep    = (double*)(base + 0x484000);  // 4 KB (512 doubles)

  hipMemsetAsync(counts, 0, 0x1010, stream);     // counts + flagc + msedel

  cb_kernel<<<KCB, 256, 0, stream>>>(lb, W, cb64T, cb32, c264, ch);
  argmax_mfma<<<NROWS / 128, 256, 0, stream>>>(z, ch, cb32,
                                               out + OUT_IDX, idxi, flagc, flagr,
                                               out + OUT_ZQ, msep, counts);
  refine_kernel<<<1024, 256, 0, stream>>>(z, cb64T, c264, cb32, flagc, flagr,
                                          idxi, out + OUT_IDX, out + OUT_ZQ,
                                          counts, msedel);
  finalize_kernel<<<1, 256, 0, stream>>>(counts, msep, msedel, out);
}

// Round 14
// 263.617 us; speedup vs baseline: 1.2400x; 1.2400x over previous
//
#include <hip/hip_runtime.h>
#include <math.h>

typedef unsigned int uint;
typedef unsigned short ushort;

#define NROWS 65536
#define KCB   1024
#define DDIM  256
#define MARGIN 0.15f

// d_out layout (floats)
#define OUT_ZQ    0
#define OUT_LOSS  16777216
#define OUT_IDX   16777217
#define OUT_PERP  16842753
#define OUT_USAGE 16842754

typedef __attribute__((ext_vector_type(8))) short s16x8;
typedef __attribute__((ext_vector_type(4))) float f32x4;
typedef __attribute__((ext_vector_type(4))) double f64x4;

__device__ __forceinline__ ushort bf16rne(float x) {
  uint u = __float_as_uint(x);
  return (ushort)((u + 0x7FFFu + ((u >> 16) & 1u)) >> 16);
}
__device__ __forceinline__ float bf2f(ushort h) {
  return __uint_as_float((uint)h << 16);
}

// ---------------------------------------------------------------------------
// Kernel 1: codebook = normalize(lb @ W.T) * 16 in fp64 (LDS-staged W);
// emits transposed fp64 (cb64T[j][k] for refine), fp32, and bf16-hi copy.
// ---------------------------------------------------------------------------
__global__ __launch_bounds__(256) void cb_kernel(const float* __restrict__ lb,
                                                 const float* __restrict__ W,
                                                 double* __restrict__ cb64T,
                                                 float* __restrict__ cb32,
                                                 double* __restrict__ c264,
                                                 ushort* __restrict__ ch) {
  const int k = blockIdx.x;
  const int t = threadIdx.x;
  __shared__ float lb_sh[256];
  __shared__ float W_sh[256 * 66];
  __shared__ double red[256];

  lb_sh[t] = lb[k * 256 + t];

  double acc = 0.0;
  for (int jt = 0; jt < 4; ++jt) {
    __syncthreads();
#pragma unroll
    for (int i = 0; i < 16; ++i) {
      int qid = t + 256 * i;
      int row = qid >> 4;
      int q   = qid & 15;
      float4 v = *(const float4*)&W[row * 256 + jt * 64 + q * 4];
      float* dst = &W_sh[row * 66 + q * 4];
      dst[0] = v.x; dst[1] = v.y; dst[2] = v.z; dst[3] = v.w;
    }
    __syncthreads();
#pragma unroll
    for (int jj = 0; jj < 64; ++jj) {
      acc += (double)lb_sh[jt * 64 + jj] * (double)W_sh[t * 66 + jj];
    }
  }

  red[t] = acc * acc;
  __syncthreads();
  for (int s = 128; s > 0; s >>= 1) {
    if (t < s) red[t] += red[t + s];
    __syncthreads();
  }
  double norm  = sqrt(red[0]);
  double scale = 16.0 / fmax(norm, 1e-12);
  double v     = acc * scale;
  cb64T[(size_t)t * 1024 + k] = v;        // transposed for refine
  float cf = (float)v;
  cb32[k * 256 + t] = cf;
  ch[k * 256 + t] = bf16rne(cf);

  __syncthreads();
  red[t] = v * v;
  __syncthreads();
  for (int s = 128; s > 0; s >>= 1) {
    if (t < s) red[t] += red[t + s];
    __syncthreads();
  }
  if (t == 0) c264[k] = red[0];
}

// ---------------------------------------------------------------------------
// Kernel 2: fused MFMA argmax + gather, 16x16x32 -- ROUND-9 CONFIG VERBATIM
// (the empirically best argmax across rounds 6-13: ~95-100us).
// score = (zh + zl) . ch; MARGIN 0.15 + exact fp64 refine.
// Per step: LDS tile = 64 codes x 64 k (ch only, 8 KB), K-major layout
// (conflict-free, linear gload_lds dest), double-buffered, 64 steps,
// 8 ds_read + 16 MFMA + 2 gload_lds / step. grid 1024 = 4 blocks/CU,
// 16 waves/CU -- TLP is the dominant term (r11/r12/r13 all regressed by
// trading waves for per-step work).
// ---------------------------------------------------------------------------
__global__ __launch_bounds__(256, 4) void argmax_mfma(const float* __restrict__ z,
                                                      const ushort* __restrict__ ch,
                                                      const float* __restrict__ cb32,
                                                      float* __restrict__ out_idx,
                                                      int* __restrict__ idx_int,
                                                      int* __restrict__ flagc,
                                                      int* __restrict__ flagr,
                                                      float* __restrict__ zq,
                                                      double* __restrict__ msep,
                                                      int* __restrict__ counts) {
  const int t     = threadIdx.x;
  const int lane  = t & 63;
  const int w     = t >> 6;
  const int ra    = lane & 15;     // z-row within wave
  const int q4    = lane >> 4;     // K 8-elem subchunk within a 32-k chunk
  const int mtile = blockIdx.x;

  __shared__ alignas(128) char cbuf[2][8192];
  __shared__ int    sidx[64];
  __shared__ double partial[4];

  // ---- z fragments: one z-row per lane, fp32 -> bf16 hi/lo in-register ----
  s16x8 zh[8], zl[8];
  const int zrow = mtile * 64 + w * 16 + ra;
#pragma unroll
  for (int c = 0; c < 8; ++c) {
    const float* zp = &z[(size_t)zrow * 256 + c * 32 + q4 * 8];
    float4 f0 = *(const float4*)zp;
    float4 f1 = *(const float4*)(zp + 4);
    float xs[8] = {f0.x, f0.y, f0.z, f0.w, f1.x, f1.y, f1.z, f1.w};
#pragma unroll
    for (int e = 0; e < 8; ++e) {
      ushort hh = bf16rne(xs[e]);
      zh[c][e] = (short)hh;
      zl[c][e] = (short)bf16rne(xs[e] - bf2f(hh));
    }
  }

  // ---- staging: 512 slots of 16B; slot s: kc=s>>8, q=(s>>6)&3, row=s&63.
  //      Linear LDS dest (wave-uniform base), per-lane global source. ----
  auto stage = [&](int buf, int nt, int kt2) {
#pragma unroll
    for (int j = 0; j < 2; ++j) {
      int s   = w * 128 + j * 64 + lane;
      int kc  = s >> 8;
      int q   = (s >> 6) & 3;
      int row = s & 63;
      const ushort* src = ch + (size_t)(nt * 64 + row) * 256 + kt2 * 64 + kc * 32 + q * 8;
      __builtin_amdgcn_global_load_lds(
          (const __attribute__((address_space(1))) void*)src,
          (__attribute__((address_space(3))) void*)(&cbuf[buf][0] + (w * 128 + j * 64) * 16),
          16, 0, 0);
    }
  };

  float m1 = -3.0e38f, m2 = -3.0e38f;
  int   i1 = 0;

  stage(0, 0, 0);
  __syncthreads();

#pragma unroll 1
  for (int nt = 0; nt < 16; ++nt) {
    f32x4 acc[4] = {f32x4(0.0f), f32x4(0.0f), f32x4(0.0f), f32x4(0.0f)};
#pragma unroll
    for (int kt2 = 0; kt2 < 4; ++kt2) {
      const int cur = (nt * 4 + kt2) & 1;
      if (kt2 < 3)      stage(cur ^ 1, nt, kt2 + 1);
      else if (nt < 15) stage(cur ^ 1, nt + 1, 0);

      const char* cbb = &cbuf[cur][0];
#pragma unroll
      for (int kc = 0; kc < 2; ++kc) {
        const s16x8 bh = zh[kt2 * 2 + kc];
        const s16x8 bl = zl[kt2 * 2 + kc];
#pragma unroll
        for (int cg = 0; cg < 4; ++cg) {
          s16x8 a = *(const s16x8*)(cbb + kc * 4096 + q4 * 1024 + (cg * 16 + ra) * 16);
          acc[cg] = __builtin_amdgcn_mfma_f32_16x16x32_bf16(a, bh, acc[cg], 0, 0, 0);
          acc[cg] = __builtin_amdgcn_mfma_f32_16x16x32_bf16(a, bl, acc[cg], 0, 0, 0);
        }
      }
      __syncthreads();
    }

    // fold this nt's 64 codes into the lane's (m1, m2, i1).
    // D layout (verified r8-r13): col = lane&15 = zrow; code = cg*16+q4*4+j.
#pragma unroll
    for (int cg = 0; cg < 4; ++cg) {
#pragma unroll
      for (int j = 0; j < 4; ++j) {
        const int code = nt * 64 + cg * 16 + q4 * 4 + j;
        float v = acc[cg][j];
        if (v > m1) { m2 = m1; m1 = v; i1 = code; }
        else        { m2 = fmaxf(m2, v); }
      }
    }
  }

  // ---- cross-lane merge across the 4 K-quarter copies of each z-row ----
#pragma unroll
  for (int off = 16; off <= 32; off <<= 1) {
    float om1 = __shfl_xor(m1, off);
    float om2 = __shfl_xor(m2, off);
    int   oi1 = __shfl_xor(i1, off);
    if (om1 > m1 || (om1 == m1 && oi1 < i1)) {
      m2 = fmaxf(m1, om2); m1 = om1; i1 = oi1;
    } else {
      m2 = fmaxf(m2, om1);
    }
  }

  if (lane < 16) {
    const int row = mtile * 64 + w * 16 + lane;
    sidx[w * 16 + lane] = i1;
    idx_int[row] = i1;
    out_idx[row] = (float)i1;
    if (m1 - m2 < MARGIN) {
      int pos = atomicAdd(flagc, 1);
      flagr[pos] = row;
    }
  }
  __syncthreads();

  // ---- fused gather: z_q write, mse partial, counts ----
  double msum = 0.0;
  for (int rr = w; rr < 64; rr += 4) {
    const int code = sidx[rr];
    const int grow = mtile * 64 + rr;
    float4 c = *(const float4*)&cb32[(size_t)code * 256 + lane * 4];
    *(float4*)&zq[(size_t)grow * 256 + lane * 4] = c;
    float4 zr = *(const float4*)&z[(size_t)grow * 256 + lane * 4];
    double d;
    d = (double)c.x - (double)zr.x; msum += d * d;
    d = (double)c.y - (double)zr.y; msum += d * d;
    d = (double)c.z - (double)zr.z; msum += d * d;
    d = (double)c.w - (double)zr.w; msum += d * d;
    if (lane == 0) atomicAdd(&counts[code], 1);
  }
#pragma unroll
  for (int off = 32; off > 0; off >>= 1) msum += __shfl_xor(msum, off);
  if (lane == 0) partial[w] = msum;
  __syncthreads();
  if (t == 0) msep[mtile] = partial[0] + partial[1] + partial[2] + partial[3];
}

// ---------------------------------------------------------------------------
// Kernel 3: exact fp64 re-solve of flagged rows (8-row batching, round-11
// verified, ~35us). Each cb64T double4 load feeds 8 rows x 4 codes = 32 f64
// FMA. Patches idx, z_q, counts, mse delta per changed row.
// ---------------------------------------------------------------------------
__global__ __launch_bounds__(256) void refine_kernel(const float* __restrict__ z,
                                                     const double* __restrict__ cb64T,
                                                     const double* __restrict__ c264,
                                                     const float* __restrict__ cb32,
                                                     const int* __restrict__ flagc,
                                                     const int* __restrict__ flagr,
                                                     int* __restrict__ idx_int,
                                                     float* __restrict__ out_idx,
                                                     float* __restrict__ zq,
                                                     int* __restrict__ counts,
                                                     double* __restrict__ msedelta) {
  const int cnt = *flagc;
  const int t   = threadIdx.x;
  __shared__ double z_sh[8][256];
  __shared__ double rs[256];
  __shared__ int    ri[256];
  __shared__ int    shI, shO;
  __shared__ double red[256];

  const int nbatch = (cnt + 7) >> 3;
  for (int b = blockIdx.x; b < nbatch; b += gridDim.x) {
    const int r0 = b * 8;
    const int nr = min(8, cnt - r0);
    __syncthreads();   // z_sh reuse across batches
#pragma unroll
    for (int r = 0; r < 8; ++r) {
      int rr = (r < nr) ? flagr[r0 + r] : flagr[r0];
      z_sh[r][t] = (double)z[(size_t)rr * DDIM + t];
    }
    __syncthreads();

    double a0[8], a1[8], a2[8], a3[8];
#pragma unroll
    for (int r = 0; r < 8; ++r) { a0[r] = 0.0; a1[r] = 0.0; a2[r] = 0.0; a3[r] = 0.0; }

#pragma unroll 1
    for (int j = 0; j < 256; j += 2) {
      f64x4 cv0 = *(const f64x4*)&cb64T[(size_t)j * 1024 + t * 4];
      f64x4 cv1 = *(const f64x4*)&cb64T[(size_t)(j + 1) * 1024 + t * 4];
#pragma unroll
      for (int r = 0; r < 8; ++r) {
        double zv = z_sh[r][j];
        a0[r] += zv * cv0[0];
        a1[r] += zv * cv0[1];
        a2[r] += zv * cv0[2];
        a3[r] += zv * cv0[3];
      }
#pragma unroll
      for (int r = 0; r < 8; ++r) {
        double zv = z_sh[r][j + 1];
        a0[r] += zv * cv1[0];
        a1[r] += zv * cv1[1];
        a2[r] += zv * cv1[2];
        a3[r] += zv * cv1[3];
      }
    }

    f64x4 c2 = *(const f64x4*)&c264[t * 4];
#pragma unroll
    for (int r = 0; r < 8; ++r) {
      if (r >= nr) continue;     // nr is block-uniform -> barriers legal
      double bb = 2.0 * a0[r] - c2[0];  int bi_ = t * 4;
      double s1 = 2.0 * a1[r] - c2[1];  if (s1 > bb) { bb = s1; bi_ = t * 4 + 1; }
      double s2 = 2.0 * a2[r] - c2[2];  if (s2 > bb) { bb = s2; bi_ = t * 4 + 2; }
      double s3 = 2.0 * a3[r] - c2[3];  if (s3 > bb) { bb = s3; bi_ = t * 4 + 3; }
      rs[t] = bb; ri[t] = bi_;
      __syncthreads();
      for (int s = 128; s > 0; s >>= 1) {
        if (t < s) {
          if (rs[t + s] > rs[t] || (rs[t + s] == rs[t] && ri[t + s] < ri[t])) {
            rs[t] = rs[t + s]; ri[t] = ri[t + s];
          }
        }
        __syncthreads();
      }
      const int row = flagr[r0 + r];
      if (t == 0) {
        int I = ri[0];
        shO = idx_int[row];
        shI = I;
        if (I != shO) {
          idx_int[row] = I;
          out_idx[row] = (float)I;
          atomicSub(&counts[shO], 1);
          atomicAdd(&counts[I], 1);
        }
      }
      __syncthreads();
      const int I = shI, O = shO;
      if (I != O) {
        float zz = (float)z_sh[r][t];
        float cn = cb32[(size_t)I * DDIM + t];
        float co = cb32[(size_t)O * DDIM + t];
        zq[(size_t)row * DDIM + t] = cn;
        double dn = (double)cn - (double)zz;
        double dd = (double)co - (double)zz;
        red[t] = dn * dn - dd * dd;
        __syncthreads();
        for (int s = 128; s > 0; s >>= 1) {
          if (t < s) red[t] += red[t + s];
          __syncthreads();
        }
        if (t == 0) atomicAdd(msedelta, red[0]);
      }
      __syncthreads();
    }
  }
}

// ---------------------------------------------------------------------------
// Kernel 4: scalars -- vq_loss, perplexity, codebook_usage.
// (msep has 1024 entries: argmax grid = NROWS/64 = 1024.)
// ---------------------------------------------------------------------------
__global__ __launch_bounds__(256) void finalize_kernel(const int* __restrict__ counts,
                                                       const double* __restrict__ msep,
                                                       const double* __restrict__ msedelta,
                                                       float* __restrict__ out) {
  const int t = threadIdx.x;
  double ms = 0.0;
#pragma unroll
  for (int i = t; i < 1024; i += 256) ms += msep[i];
  if (t == 0) ms += *msedelta;

  double ent = 0.0;
  int used = 0;
#pragma unroll
  for (int i = t; i < KCB; i += 256) {
    int c = counts[i];
    if (c > 0) used++;
    double p = (double)c / (double)NROWS;
    ent += p * log(p + 1e-10);
  }
  __shared__ double se[256];
  __shared__ double sm[256];
  __shared__ int    su[256];
  se[t] = ent; sm[t] = ms; su[t] = used;
  __syncthreads();
  for (int s = 128; s > 0; s >>= 1) {
    if (t < s) { se[t] += se[t + s]; sm[t] += sm[t + s]; su[t] += su[t + s]; }
    __syncthreads();
  }
  if (t == 0) {
    double mse = sm[0] / ((double)NROWS * (double)DDIM);
    out[OUT_LOSS]  = (float)(1.25 * mse);
    out[OUT_PERP]  = (float)exp(-se[0]);
    out[OUT_USAGE] = (float)((double)su[0] / (double)KCB);
  }
}

// ---------------------------------------------------------------------------
extern "C" void kernel_launch(void* const* d_in, const int* in_sizes, int n_in,
                              void* d_out, int out_size, void* d_ws, size_t ws_size,
                              hipStream_t stream) {
  const float* z  = (const float*)d_in[0];   // [65536][256]
  const float* lb = (const float*)d_in[1];   // [1024][256]
  const float* W  = (const float*)d_in[2];   // [256][256]
  float* out = (float*)d_out;

  char* base = (char*)d_ws;
  double* cb64T   = (double*)(base + 0x000000);  // 2 MB (transposed [j][k])
  ushort* ch      = (ushort*)(base + 0x200000);  // 512 KB
  float*  cb32    = (float*) (base + 0x300000);  // 1 MB
  double* c264    = (double*)(base + 0x400000);  // 8 KB
  int*    idxi    = (int*)   (base + 0x402000);  // 256 KB
  int*    flagr   = (int*)   (base + 0x442000);  // 256 KB
  int*    counts  = (int*)   (base + 0x482000);  // 4 KB   } one zeroed
  int*    flagc   = (int*)   (base + 0x483000);  // 4 B    } contiguous
  double* msedel  = (double*)(base + 0x483008);  // 8 B    } region
  double* msep    = (double*)(base + 0x484000);  // 8 KB (1024 doubles)

  hipMemsetAsync(counts, 0, 0x1010, stream);     // counts + flagc + msedel

  cb_kernel<<<KCB, 256, 0, stream>>>(lb, W, cb64T, cb32, c264, ch);
  argmax_mfma<<<NROWS / 64, 256, 0, stream>>>(z, ch, cb32,
                                              out + OUT_IDX, idxi, flagc, flagr,
                                              out + OUT_ZQ, msep, counts);
  refine_kernel<<<1024, 256, 0, stream>>>(z, cb64T, c264, cb32, flagc, flagr,
                                          idxi, out + OUT_IDX, out + OUT_ZQ,
                                          counts, msedel);
  finalize_kernel<<<1, 256, 0, stream>>>(counts, msep, msedel, out);
}

// Round 15
// 258.089 us; speedup vs baseline: 1.2666x; 1.0214x over previous
//
#include <hip/hip_runtime.h>
#include <math.h>

typedef unsigned int uint;
typedef unsigned short ushort;

#define NROWS 65536
#define KCB   1024
#define DDIM  256
#define MARGIN 0.15f

// d_out layout (floats)
#define OUT_ZQ    0
#define OUT_LOSS  16777216
#define OUT_IDX   16777217
#define OUT_PERP  16842753
#define OUT_USAGE 16842754

typedef __attribute__((ext_vector_type(8))) short s16x8;
typedef __attribute__((ext_vector_type(4))) float f32x4;
typedef __attribute__((ext_vector_type(4))) double f64x4;

__device__ __forceinline__ ushort bf16rne(float x) {
  uint u = __float_as_uint(x);
  return (ushort)((u + 0x7FFFu + ((u >> 16) & 1u)) >> 16);
}
__device__ __forceinline__ float bf2f(ushort h) {
  return __uint_as_float((uint)h << 16);
}

// ---------------------------------------------------------------------------
// Kernel 1: codebook = normalize(lb @ W.T) * 16 in fp64 (LDS-staged W);
// emits transposed fp64 (cb64T[j][k] for refine), fp32, and bf16-hi copy.
// Round-15: block 0 also zeroes counts/flagc/msedel (memset launch removed;
// consumers all run in later kernels on the same stream).
// ---------------------------------------------------------------------------
__global__ __launch_bounds__(256) void cb_kernel(const float* __restrict__ lb,
                                                 const float* __restrict__ W,
                                                 double* __restrict__ cb64T,
                                                 float* __restrict__ cb32,
                                                 double* __restrict__ c264,
                                                 ushort* __restrict__ ch,
                                                 int* __restrict__ counts,
                                                 int* __restrict__ flagc,
                                                 double* __restrict__ msedel) {
  const int k = blockIdx.x;
  const int t = threadIdx.x;
  __shared__ float lb_sh[256];
  __shared__ float W_sh[256 * 66];
  __shared__ double red[256];

  if (k == 0) {
#pragma unroll
    for (int i = 0; i < 4; ++i) counts[t + 256 * i] = 0;
    if (t == 0) { *flagc = 0; *msedel = 0.0; }
  }

  lb_sh[t] = lb[k * 256 + t];

  double acc = 0.0;
  for (int jt = 0; jt < 4; ++jt) {
    __syncthreads();
#pragma unroll
    for (int i = 0; i < 16; ++i) {
      int qid = t + 256 * i;
      int row = qid >> 4;
      int q   = qid & 15;
      float4 v = *(const float4*)&W[row * 256 + jt * 64 + q * 4];
      float* dst = &W_sh[row * 66 + q * 4];
      dst[0] = v.x; dst[1] = v.y; dst[2] = v.z; dst[3] = v.w;
    }
    __syncthreads();
#pragma unroll
    for (int jj = 0; jj < 64; ++jj) {
      acc += (double)lb_sh[jt * 64 + jj] * (double)W_sh[t * 66 + jj];
    }
  }

  red[t] = acc * acc;
  __syncthreads();
  for (int s = 128; s > 0; s >>= 1) {
    if (t < s) red[t] += red[t + s];
    __syncthreads();
  }
  double norm  = sqrt(red[0]);
  double scale = 16.0 / fmax(norm, 1e-12);
  double v     = acc * scale;
  cb64T[(size_t)t * 1024 + k] = v;        // transposed for refine
  float cf = (float)v;
  cb32[k * 256 + t] = cf;
  ch[k * 256 + t] = bf16rne(cf);

  __syncthreads();
  red[t] = v * v;
  __syncthreads();
  for (int s = 128; s > 0; s >>= 1) {
    if (t < s) red[t] += red[t + s];
    __syncthreads();
  }
  if (t == 0) c264[k] = red[0];
}

// ---------------------------------------------------------------------------
// Kernel 2: fused MFMA argmax + gather, 16x16x32 (round-15).
// Geometry = round-9/14 verbatim (the measured best: 64-code x 64-k 8 KB
// tiles, 4 blocks/CU, 16 waves/CU). ONE change: counted-vmcnt pipeline at
// ISO-OCCUPANCY -- 3 buffers (24 KB), one raw s_barrier per step, vmcnt(2)
// (vmcnt(0) only at the last step), stage issued 2 steps ahead. r7's version
// of this regressed but was confounded by occupancy 2; this is the clean A/B
// against r14's per-step vmcnt(0) drain.
// WAR safety: stage(s+2) is issued only after the step-s barrier, which all
// waves reach only after consuming buf (s+2)%3's previous tile (their
// ds_reads complete before their last MFMA consumes them); per-wave vmcnt(2)
// BEFORE the barrier guarantees every wave's tile-s loads have landed.
// ---------------------------------------------------------------------------
__global__ __launch_bounds__(256, 4) void argmax_mfma(const float* __restrict__ z,
                                                      const ushort* __restrict__ ch,
                                                      const float* __restrict__ cb32,
                                                      float* __restrict__ out_idx,
                                                      int* __restrict__ idx_int,
                                                      int* __restrict__ flagc,
                                                      int* __restrict__ flagr,
                                                      float* __restrict__ zq,
                                                      double* __restrict__ msep,
                                                      int* __restrict__ counts) {
  const int t     = threadIdx.x;
  const int lane  = t & 63;
  const int w     = t >> 6;
  const int ra    = lane & 15;     // z-row within wave
  const int q4    = lane >> 4;     // K 8-elem subchunk within a 32-k chunk
  const int mtile = blockIdx.x;

  __shared__ alignas(128) char cbuf[3][8192];
  __shared__ int    sidx[64];
  __shared__ double partial[4];

  // ---- z fragments: one z-row per lane, fp32 -> bf16 hi/lo in-register ----
  s16x8 zh[8], zl[8];
  const int zrow = mtile * 64 + w * 16 + ra;
#pragma unroll
  for (int c = 0; c < 8; ++c) {
    const float* zp = &z[(size_t)zrow * 256 + c * 32 + q4 * 8];
    float4 f0 = *(const float4*)zp;
    float4 f1 = *(const float4*)(zp + 4);
    float xs[8] = {f0.x, f0.y, f0.z, f0.w, f1.x, f1.y, f1.z, f1.w};
#pragma unroll
    for (int e = 0; e < 8; ++e) {
      ushort hh = bf16rne(xs[e]);
      zh[c][e] = (short)hh;
      zl[c][e] = (short)bf16rne(xs[e] - bf2f(hh));
    }
  }

  // ---- staging: 512 slots of 16B; slot s: kc=s>>8, q=(s>>6)&3, row=s&63.
  //      Linear LDS dest (wave-uniform base), per-lane global source. ----
  auto stage = [&](int buf, int step) {
    const int nt  = step >> 2;
    const int kt2 = step & 3;
#pragma unroll
    for (int j = 0; j < 2; ++j) {
      int s   = w * 128 + j * 64 + lane;
      int kc  = s >> 8;
      int q   = (s >> 6) & 3;
      int row = s & 63;
      const ushort* src = ch + (size_t)(nt * 64 + row) * 256 + kt2 * 64 + kc * 32 + q * 8;
      __builtin_amdgcn_global_load_lds(
          (const __attribute__((address_space(1))) void*)src,
          (__attribute__((address_space(3))) void*)(&cbuf[0][0] + buf * 8192 + (w * 128 + j * 64) * 16),
          16, 0, 0);
    }
  };

  float m1 = -3.0e38f, m2 = -3.0e38f;
  int   i1 = 0;

  stage(0, 0);
  stage(1, 1);

#pragma unroll 1
  for (int nt = 0; nt < 16; ++nt) {
    f32x4 acc[4] = {f32x4(0.0f), f32x4(0.0f), f32x4(0.0f), f32x4(0.0f)};
#pragma unroll
    for (int kt2 = 0; kt2 < 4; ++kt2) {
      const int step = nt * 4 + kt2;
      // counted wait: tile `step` landed (oldest 2 loads); stage(step+1)
      // may stay in flight across the barrier. Drain fully only at the end.
      if (step != 63) asm volatile("s_waitcnt vmcnt(2)" ::: "memory");
      else            asm volatile("s_waitcnt vmcnt(0)" ::: "memory");
      __builtin_amdgcn_s_barrier();
      __builtin_amdgcn_sched_barrier(0);
      if (step < 62) stage((step + 2) % 3, step + 2);

      const char* cbb = &cbuf[0][0] + (step % 3) * 8192;
#pragma unroll
      for (int kc = 0; kc < 2; ++kc) {
        const s16x8 bh = zh[kt2 * 2 + kc];
        const s16x8 bl = zl[kt2 * 2 + kc];
#pragma unroll
        for (int cg = 0; cg < 4; ++cg) {
          s16x8 a = *(const s16x8*)(cbb + kc * 4096 + q4 * 1024 + (cg * 16 + ra) * 16);
          acc[cg] = __builtin_amdgcn_mfma_f32_16x16x32_bf16(a, bh, acc[cg], 0, 0, 0);
          acc[cg] = __builtin_amdgcn_mfma_f32_16x16x32_bf16(a, bl, acc[cg], 0, 0, 0);
        }
      }
    }

    // fold this nt's 64 codes into the lane's (m1, m2, i1).
    // D layout (verified r8-r14): col = lane&15 = zrow; code = cg*16+q4*4+j.
#pragma unroll
    for (int cg = 0; cg < 4; ++cg) {
#pragma unroll
      for (int j = 0; j < 4; ++j) {
        const int code = nt * 64 + cg * 16 + q4 * 4 + j;
        float v = acc[cg][j];
        if (v > m1) { m2 = m1; m1 = v; i1 = code; }
        else        { m2 = fmaxf(m2, v); }
      }
    }
  }

  // ---- cross-lane merge across the 4 K-quarter copies of each z-row ----
#pragma unroll
  for (int off = 16; off <= 32; off <<= 1) {
    float om1 = __shfl_xor(m1, off);
    float om2 = __shfl_xor(m2, off);
    int   oi1 = __shfl_xor(i1, off);
    if (om1 > m1 || (om1 == m1 && oi1 < i1)) {
      m2 = fmaxf(m1, om2); m1 = om1; i1 = oi1;
    } else {
      m2 = fmaxf(m2, om1);
    }
  }

  if (lane < 16) {
    const int row = mtile * 64 + w * 16 + lane;
    sidx[w * 16 + lane] = i1;
    idx_int[row] = i1;
    out_idx[row] = (float)i1;
    if (m1 - m2 < MARGIN) {
      int pos = atomicAdd(flagc, 1);
      flagr[pos] = row;
    }
  }
  __syncthreads();

  // ---- fused gather: z_q write, mse partial, counts ----
  double msum = 0.0;
  for (int rr = w; rr < 64; rr += 4) {
    const int code = sidx[rr];
    const int grow = mtile * 64 + rr;
    float4 c = *(const float4*)&cb32[(size_t)code * 256 + lane * 4];
    *(float4*)&zq[(size_t)grow * 256 + lane * 4] = c;
    float4 zr = *(const float4*)&z[(size_t)grow * 256 + lane * 4];
    double d;
    d = (double)c.x - (double)zr.x; msum += d * d;
    d = (double)c.y - (double)zr.y; msum += d * d;
    d = (double)c.z - (double)zr.z; msum += d * d;
    d = (double)c.w - (double)zr.w; msum += d * d;
    if (lane == 0) atomicAdd(&counts[code], 1);
  }
#pragma unroll
  for (int off = 32; off > 0; off >>= 1) msum += __shfl_xor(msum, off);
  if (lane == 0) partial[w] = msum;
  __syncthreads();
  if (t == 0) msep[mtile] = partial[0] + partial[1] + partial[2] + partial[3];
}

// ---------------------------------------------------------------------------
// Kernel 3: exact fp64 re-solve of flagged rows (8-row batching, round-11
// verified). Each cb64T double4 load feeds 8 rows x 4 codes = 32 f64 FMA.
// Patches idx, z_q, counts, mse delta per changed row.
// ---------------------------------------------------------------------------
__global__ __launch_bounds__(256) void refine_kernel(const float* __restrict__ z,
                                                     const double* __restrict__ cb64T,
                                                     const double* __restrict__ c264,
                                                     const float* __restrict__ cb32,
                                                     const int* __restrict__ flagc,
                                                     const int* __restrict__ flagr,
                                                     int* __restrict__ idx_int,
                                                     float* __restrict__ out_idx,
                                                     float* __restrict__ zq,
                                                     int* __restrict__ counts,
                                                     double* __restrict__ msedelta) {
  const int cnt = *flagc;
  const int t   = threadIdx.x;
  __shared__ double z_sh[8][256];
  __shared__ double rs[256];
  __shared__ int    ri[256];
  __shared__ int    shI, shO;
  __shared__ double red[256];

  const int nbatch = (cnt + 7) >> 3;
  for (int b = blockIdx.x; b < nbatch; b += gridDim.x) {
    const int r0 = b * 8;
    const int nr = min(8, cnt - r0);
    __syncthreads();   // z_sh reuse across batches
#pragma unroll
    for (int r = 0; r < 8; ++r) {
      int rr = (r < nr) ? flagr[r0 + r] : flagr[r0];
      z_sh[r][t] = (double)z[(size_t)rr * DDIM + t];
    }
    __syncthreads();

    double a0[8], a1[8], a2[8], a3[8];
#pragma unroll
    for (int r = 0; r < 8; ++r) { a0[r] = 0.0; a1[r] = 0.0; a2[r] = 0.0; a3[r] = 0.0; }

#pragma unroll 1
    for (int j = 0; j < 256; j += 2) {
      f64x4 cv0 = *(const f64x4*)&cb64T[(size_t)j * 1024 + t * 4];
      f64x4 cv1 = *(const f64x4*)&cb64T[(size_t)(j + 1) * 1024 + t * 4];
#pragma unroll
      for (int r = 0; r < 8; ++r) {
        double zv = z_sh[r][j];
        a0[r] += zv * cv0[0];
        a1[r] += zv * cv0[1];
        a2[r] += zv * cv0[2];
        a3[r] += zv * cv0[3];
      }
#pragma unroll
      for (int r = 0; r < 8; ++r) {
        double zv = z_sh[r][j + 1];
        a0[r] += zv * cv1[0];
        a1[r] += zv * cv1[1];
        a2[r] += zv * cv1[2];
        a3[r] += zv * cv1[3];
      }
    }

    f64x4 c2 = *(const f64x4*)&c264[t * 4];
#pragma unroll
    for (int r = 0; r < 8; ++r) {
      if (r >= nr) continue;     // nr is block-uniform -> barriers legal
      double bb = 2.0 * a0[r] - c2[0];  int bi_ = t * 4;
      double s1 = 2.0 * a1[r] - c2[1];  if (s1 > bb) { bb = s1; bi_ = t * 4 + 1; }
      double s2 = 2.0 * a2[r] - c2[2];  if (s2 > bb) { bb = s2; bi_ = t * 4 + 2; }
      double s3 = 2.0 * a3[r] - c2[3];  if (s3 > bb) { bb = s3; bi_ = t * 4 + 3; }
      rs[t] = bb; ri[t] = bi_;
      __syncthreads();
      for (int s = 128; s > 0; s >>= 1) {
        if (t < s) {
          if (rs[t + s] > rs[t] || (rs[t + s] == rs[t] && ri[t + s] < ri[t])) {
            rs[t] = rs[t + s]; ri[t] = ri[t + s];
          }
        }
        __syncthreads();
      }
      const int row = flagr[r0 + r];
      if (t == 0) {
        int I = ri[0];
        shO = idx_int[row];
        shI = I;
        if (I != shO) {
          idx_int[row] = I;
          out_idx[row] = (float)I;
          atomicSub(&counts[shO], 1);
          atomicAdd(&counts[I], 1);
        }
      }
      __syncthreads();
      const int I = shI, O = shO;
      if (I != O) {
        float zz = (float)z_sh[r][t];
        float cn = cb32[(size_t)I * DDIM + t];
        float co = cb32[(size_t)O * DDIM + t];
        zq[(size_t)row * DDIM + t] = cn;
        double dn = (double)cn - (double)zz;
        double dd = (double)co - (double)zz;
        red[t] = dn * dn - dd * dd;
        __syncthreads();
        for (int s = 128; s > 0; s >>= 1) {
          if (t < s) red[t] += red[t + s];
          __syncthreads();
        }
        if (t == 0) atomicAdd(msedelta, red[0]);
      }
      __syncthreads();
    }
  }
}

// ---------------------------------------------------------------------------
// Kernel 4: scalars -- vq_loss, perplexity, codebook_usage.
// (msep has 1024 entries: argmax grid = NROWS/64 = 1024.)
// ---------------------------------------------------------------------------
__global__ __launch_bounds__(256) void finalize_kernel(const int* __restrict__ counts,
                                                       const double* __restrict__ msep,
                                                       const double* __restrict__ msedelta,
                                                       float* __restrict__ out) {
  const int t = threadIdx.x;
  double ms = 0.0;
#pragma unroll
  for (int i = t; i < 1024; i += 256) ms += msep[i];
  if (t == 0) ms += *msedelta;

  double ent = 0.0;
  int used = 0;
#pragma unroll
  for (int i = t; i < KCB; i += 256) {
    int c = counts[i];
    if (c > 0) used++;
    double p = (double)c / (double)NROWS;
    ent += p * log(p + 1e-10);
  }
  __shared__ double se[256];
  __shared__ double sm[256];
  __shared__ int    su[256];
  se[t] = ent; sm[t] = ms; su[t] = used;
  __syncthreads();
  for (int s = 128; s > 0; s >>= 1) {
    if (t < s) { se[t] += se[t + s]; sm[t] += sm[t + s]; su[t] += su[t + s]; }
    __syncthreads();
  }
  if (t == 0) {
    double mse = sm[0] / ((double)NROWS * (double)DDIM);
    out[OUT_LOSS]  = (float)(1.25 * mse);
    out[OUT_PERP]  = (float)exp(-se[0]);
    out[OUT_USAGE] = (float)((double)su[0] / (double)KCB);
  }
}

// ---------------------------------------------------------------------------
extern "C" void kernel_launch(void* const* d_in, const int* in_sizes, int n_in,
                              void* d_out, int out_size, void* d_ws, size_t ws_size,
                              hipStream_t stream) {
  const float* z  = (const float*)d_in[0];   // [65536][256]
  const float* lb = (const float*)d_in[1];   // [1024][256]
  const float* W  = (const float*)d_in[2];   // [256][256]
  float* out = (float*)d_out;

  char* base = (char*)d_ws;
  double* cb64T   = (double*)(base + 0x000000);  // 2 MB (transposed [j][k])
  ushort* ch      = (ushort*)(base + 0x200000);  // 512 KB
  float*  cb32    = (float*) (base + 0x300000);  // 1 MB
  double* c264    = (double*)(base + 0x400000);  // 8 KB
  int*    idxi    = (int*)   (base + 0x402000);  // 256 KB
  int*    flagr   = (int*)   (base + 0x442000);  // 256 KB
  int*    counts  = (int*)   (base + 0x482000);  // 4 KB
  int*    flagc   = (int*)   (base + 0x483000);  // 4 B
  double* msedel  = (double*)(base + 0x483008);  // 8 B
  double* msep    = (double*)(base + 0x484000);  // 8 KB (1024 doubles)

  cb_kernel<<<KCB, 256, 0, stream>>>(lb, W, cb64T, cb32, c264, ch,
                                     counts, flagc, msedel);
  argmax_mfma<<<NROWS / 64, 256, 0, stream>>>(z, ch, cb32,
                                              out + OUT_IDX, idxi, flagc, flagr,
                                              out + OUT_ZQ, msep, counts);
  refine_kernel<<<1024, 256, 0, stream>>>(z, cb64T, c264, cb32, flagc, flagr,
                                          idxi, out + OUT_IDX, out + OUT_ZQ,
                                          counts, msedel);
  finalize_kernel<<<1, 256, 0, stream>>>(counts, msep, msedel, out);
}